// Round 1
// 2069.427 us; speedup vs baseline: 1.3032x; 1.3032x over previous
//
#include <hip/hip_runtime.h>
#include <stdint.h>

#define K_QUEUE 65536
#define B_ROWS 128
#define C_DIM 768
#define NB 8192          // value buckets per row for negative sort
#define POS_CAP 4096     // max positives per row we handle (actual ~1024)
#define RS_THREADS 512

static constexpr float INV_T = 1.0f / 0.3f;

typedef short s8v __attribute__((ext_vector_type(8)));
typedef float f4v __attribute__((ext_vector_type(4)));

__device__ __forceinline__ unsigned short f2bf(float f) {
  unsigned u = __builtin_bit_cast(unsigned, f);
  unsigned r = (u + 0x7FFFu + ((u >> 16) & 1u)) >> 16;  // round-to-nearest-even
  return (unsigned short)r;
}

// monotonic float->uint (ascending) and inverse
__device__ __forceinline__ unsigned ford(float f) {
  unsigned u = __builtin_bit_cast(unsigned, f);
  return (u & 0x80000000u) ? ~u : (u | 0x80000000u);
}
__device__ __forceinline__ float ford_inv(unsigned u) {
  unsigned v = (u & 0x80000000u) ? (u & 0x7FFFFFFFu) : ~u;
  return __builtin_bit_cast(float, v);
}

// ---------------- setup: label histogram -> pos_min/neg_min/reps ----------------
__global__ void k_setup(const int* __restrict__ label_q,
                        const int* __restrict__ label_queue,
                        const int* __restrict__ top_k_p,
                        int* __restrict__ meta, int* __restrict__ poscount) {
  __shared__ int hist[64];
  __shared__ int s_min, s_max;
  int t = threadIdx.x;
  if (t < 64) hist[t] = 0;
  if (t == 0) { s_min = 1 << 30; s_max = 0; }
  __syncthreads();
  for (int i = t; i < K_QUEUE; i += 256) atomicAdd(&hist[label_queue[i] & 63], 1);
  __syncthreads();
  if (t < B_ROWS) {
    int pc = hist[label_q[t] & 63];
    poscount[t] = pc;
    atomicMin(&s_min, pc);
    atomicMax(&s_max, pc);
  }
  __syncthreads();
  if (t == 0) {
    int pos_min = s_min;
    int neg_min = K_QUEUE - s_max;
    int tk = top_k_p[0];
    int reps = ((pos_min < tk) ? pos_min : tk) + 1;
    meta[0] = pos_min; meta[1] = neg_min; meta[2] = reps;
  }
}

// ---------------- convert liner_q fp32 -> bf16 ----------------
__global__ void k_cvtA(const float* __restrict__ A, unsigned short* __restrict__ Abf) {
  int i = blockIdx.x * blockDim.x + threadIdx.x;
  if (i < B_ROWS * C_DIM) Abf[i] = f2bf(A[i]);
}

// ---------------- GEMM: scores[128][65536] = A(128x768) * Bq(65536x768)^T ----------------
// block tile: M=128 (all rows) x N=64, 4 waves, each wave owns a 16-wide n-slice.
// mfma_f32_16x16x32_bf16: A frag A[m=lane&15][k=(lane>>4)*8+j]; B frag B[k][n=lane&15];
// D: col=lane&15, row=(lane>>4)*4+reg  (HW-verified mappings per guide m89/m91).
#define BK 32
#define LDA 48  // padded LDS row stride (elems); keeps 16B alignment, breaks pow2 conflicts
__global__ __launch_bounds__(256) void k_gemm(const unsigned short* __restrict__ Abf,
                                              const float* __restrict__ Bq,
                                              float* __restrict__ scores) {
  __shared__ unsigned short As[128 * LDA];
  __shared__ unsigned short Bs[64 * LDA];
  int t = threadIdx.x;
  int wave = t >> 6, lane = t & 63;
  int q = lane >> 4, lr = lane & 15;
  int n0 = blockIdx.x * 64;

  f4v acc[8];
#pragma unroll
  for (int i = 0; i < 8; i++) acc[i] = (f4v){0.f, 0.f, 0.f, 0.f};

  for (int k0 = 0; k0 < C_DIM; k0 += BK) {
    // stage A: 128x32 bf16 (512 chunks of 8 elems = 16B)
#pragma unroll
    for (int c = t; c < 512; c += 256) {
      int m = c >> 2, ko = (c & 3) * 8;
      s8v v = *(const s8v*)(Abf + (size_t)m * C_DIM + k0 + ko);
      *(s8v*)(As + m * LDA + ko) = v;
    }
    // stage B: 64x32, fp32 -> bf16 (512 chunks of 4 floats)
#pragma unroll
    for (int c = t; c < 512; c += 256) {
      int n = c >> 3, ko = (c & 7) * 4;
      float4 v = *(const float4*)(Bq + (size_t)(n0 + n) * C_DIM + k0 + ko);
      unsigned lo = (unsigned)f2bf(v.x) | ((unsigned)f2bf(v.y) << 16);
      unsigned hi = (unsigned)f2bf(v.z) | ((unsigned)f2bf(v.w) << 16);
      *(uint2*)(Bs + n * LDA + ko) = make_uint2(lo, hi);
    }
    __syncthreads();
    s8v bfrag = *(const s8v*)(Bs + (wave * 16 + lr) * LDA + q * 8);
#pragma unroll
    for (int mt = 0; mt < 8; mt++) {
      s8v afrag = *(const s8v*)(As + (mt * 16 + lr) * LDA + q * 8);
      acc[mt] = __builtin_amdgcn_mfma_f32_16x16x32_bf16(afrag, bfrag, acc[mt], 0, 0, 0);
    }
    __syncthreads();
  }
  int n = n0 + wave * 16 + lr;
#pragma unroll
  for (int mt = 0; mt < 8; mt++)
#pragma unroll
    for (int r = 0; r < 4; r++) {
      int m = mt * 16 + q * 4 + r;
      scores[(size_t)m * K_QUEUE + n] = acc[mt][r];
    }
}

// ---------------- per-row: compact positives, bucket-sort negatives ----------------
__global__ __launch_bounds__(RS_THREADS) void k_rowsort(
    const float* __restrict__ scores, const int* __restrict__ label_q,
    const int* __restrict__ label_queue, float* __restrict__ neg_sorted,
    int* __restrict__ bucket_off, float* __restrict__ pos_buf) {
  __shared__ unsigned hist[NB];
  __shared__ unsigned tsum[RS_THREADS];
  __shared__ unsigned s_minu, s_maxu;
  __shared__ int s_pcnt;

  int b = blockIdx.x, t = threadIdx.x;
  const float* row = scores + (size_t)b * K_QUEUE;
  int myl = label_q[b];

  if (t == 0) { s_minu = 0xFFFFFFFFu; s_maxu = 0u; s_pcnt = 0; }
  for (int i = t; i < NB; i += RS_THREADS) hist[i] = 0u;
  __syncthreads();

  // pass 0: neg min/max + compact positives (order arbitrary; sorted later)
  unsigned lmin = 0xFFFFFFFFu, lmax = 0u;
  for (int i = t; i < K_QUEUE; i += RS_THREADS) {
    float v = row[i];
    if (label_queue[i] == myl) {
      int p = atomicAdd(&s_pcnt, 1);
      if (p < POS_CAP) pos_buf[(size_t)b * POS_CAP + p] = v;
    } else {
      unsigned u = ford(v);
      lmin = min(lmin, u);
      lmax = max(lmax, u);
    }
  }
  atomicMin(&s_minu, lmin);
  atomicMax(&s_maxu, lmax);
  __syncthreads();
  float minv = ford_inv(s_minu), maxv = ford_inv(s_maxu);
  float scale = (float)(NB - 1) / fmaxf(maxv - minv, 1e-30f);

  // pass 1: bucket histogram over negatives (descending buckets)
  for (int i = t; i < K_QUEUE; i += RS_THREADS) {
    if (label_queue[i] != myl) {
      float v = row[i];
      int bk = (int)((maxv - v) * scale);
      bk = min(max(bk, 0), NB - 1);
      atomicAdd(&hist[bk], 1u);
    }
  }
  __syncthreads();

  // pass 2: exclusive scan of 8192 bins (16 bins/thread + block scan)
  unsigned local[16];
  unsigned sum = 0;
#pragma unroll
  for (int j = 0; j < 16; j++) { local[j] = hist[t * 16 + j]; sum += local[j]; }
  tsum[t] = sum;
  __syncthreads();
  for (int off = 1; off < RS_THREADS; off <<= 1) {
    unsigned v = (t >= off) ? tsum[t - off] : 0u;
    __syncthreads();
    tsum[t] += v;
    __syncthreads();
  }
  unsigned run = tsum[t] - sum;
  int* boff = bucket_off + (size_t)b * (NB + 1);
#pragma unroll
  for (int j = 0; j < 16; j++) {
    unsigned c = local[j];
    hist[t * 16 + j] = run;       // scatter cursor
    boff[t * 16 + j] = (int)run;  // persisted for per-bucket sort
    run += c;
  }
  if (t == RS_THREADS - 1) boff[NB] = (int)run;  // = negcount
  __syncthreads();

  // pass 3: scatter negatives into bucket slots
  for (int i = t; i < K_QUEUE; i += RS_THREADS) {
    if (label_queue[i] != myl) {
      float v = row[i];
      int bk = (int)((maxv - v) * scale);
      bk = min(max(bk, 0), NB - 1);
      unsigned p = atomicAdd(&hist[bk], 1u);
      neg_sorted[(size_t)b * K_QUEUE + p] = v;
    }
  }
}

// ---------------- per-bucket insertion sort (descending) in LDS ----------------
// One block sorts a contiguous chunk of BS_BUCKETS buckets. The chunk's elements
// are contiguous in neg_sorted, so load/store are coalesced streams; the serial
// dependent accesses of the insertion sort hit LDS (~5 cyc) instead of HBM
// (~200-900 cyc). Worst-case center chunk for a gaussian score distribution is
// ~7.3K floats; BS_CAP=12288 gives 1.7x margin. Overflow falls back to the old
// global-memory path (correct, just slow; never expected to trigger).
#define BS_BUCKETS 256
#define BS_CAP 12288  // floats -> 48 KB LDS, 3 blocks/CU
__global__ __launch_bounds__(256) void k_bsort(float* __restrict__ neg_sorted,
                                               const int* __restrict__ bucket_off) {
  __shared__ float sv[BS_CAP];
  int b = blockIdx.y;
  int bin0 = blockIdx.x * BS_BUCKETS;
  const int* boff = bucket_off + (size_t)b * (NB + 1);
  int s = boff[bin0], e = boff[bin0 + BS_BUCKETS];
  int n = e - s;
  float* a = neg_sorted + (size_t)b * K_QUEUE;
  int t = threadIdx.x;
  int bin = bin0 + t;  // one bucket per thread (BS_BUCKETS == blockDim.x)
  int bs = boff[bin], be = boff[bin + 1];

  if (n <= BS_CAP) {
    // coalesced load chunk into LDS
    for (int i = t; i < n; i += 256) sv[i] = a[s + i];
    __syncthreads();
    // insertion sort own bucket in LDS (descending)
    for (int i = bs - s + 1; i < be - s; i++) {
      float v = sv[i];
      int j = i - 1;
      while (j >= bs - s && sv[j] < v) { sv[j + 1] = sv[j]; j--; }
      sv[j + 1] = v;
    }
    __syncthreads();
    // coalesced store back
    for (int i = t; i < n; i += 256) a[s + i] = sv[i];
  } else {
    // fallback: sort in global memory (original path)
    for (int i = bs + 1; i < be; i++) {
      float v = a[i];
      int j = i - 1;
      while (j >= bs && a[j] < v) { a[j + 1] = a[j]; j--; }
      a[j + 1] = v;
    }
  }
}

// ---------------- positives: bitonic sort (descending) per row in LDS ----------------
__global__ __launch_bounds__(256) void k_psort(float* __restrict__ pos_buf,
                                               const int* __restrict__ poscount) {
  __shared__ float sv[POS_CAP];
  int b = blockIdx.x, t = threadIdx.x;
  int pc = min(poscount[b], POS_CAP);
  float* pb = pos_buf + (size_t)b * POS_CAP;
  for (int i = t; i < POS_CAP; i += 256) sv[i] = (i < pc) ? pb[i] : -__builtin_inff();
  __syncthreads();
  for (int ksz = 2; ksz <= POS_CAP; ksz <<= 1) {
    for (int j = ksz >> 1; j > 0; j >>= 1) {
      for (int e = t; e < POS_CAP; e += 256) {
        int p = e ^ j;
        if (p > e) {
          bool up = (e & ksz) != 0;  // ascending region; final pass: descending
          float a0 = sv[e], a1 = sv[p];
          bool sw = up ? (a0 > a1) : (a0 < a1);
          if (sw) { sv[e] = a1; sv[p] = a0; }
        }
      }
      __syncthreads();
    }
  }
  for (int i = t; i < POS_CAP; i += 256) pb[i] = sv[i];
}

// ---------------- assemble output: out[b*reps+r] = [pos_cat, neg_sorted[b][0:neg_min]] / T --
#define ASM_COLS 1024
__global__ __launch_bounds__(256) void k_assemble(const float* __restrict__ neg_sorted,
                                                  const float* __restrict__ pos_buf,
                                                  const int* __restrict__ meta,
                                                  float* __restrict__ out) {
  int pos_min = meta[0], neg_min = meta[1], reps = meta[2];
  int row = blockIdx.y;
  if (row >= B_ROWS * reps) return;
  int L = 1 + neg_min;
  int c0 = blockIdx.x * ASM_COLS;
  if (c0 >= L) return;
  int b = row / reps;
  int r = row - b * reps;
  size_t obase = (size_t)row * (size_t)L;
  const float* ns = neg_sorted + (size_t)b * K_QUEUE;
  if (c0 == 0 && threadIdx.x == 0) {
    const float* pb = pos_buf + (size_t)b * POS_CAP;
    float pv = (r < reps - 1) ? pb[r] : pb[pos_min - 1];
    out[obase] = pv * INV_T;
  }
  int cend = min(c0 + ASM_COLS, L);
  for (int c = c0 + (int)threadIdx.x; c < cend; c += 256) {
    if (c >= 1) out[obase + c] = ns[c - 1] * INV_T;
  }
}

// ---------------- launch ----------------
extern "C" void kernel_launch(void* const* d_in, const int* in_sizes, int n_in,
                              void* d_out, int out_size, void* d_ws, size_t ws_size,
                              hipStream_t stream) {
  const float* liner_q = (const float*)d_in[0];
  const float* feature_queue = (const float*)d_in[1];
  const int* label_q = (const int*)d_in[2];
  const int* label_queue = (const int*)d_in[3];
  const int* top_k = (const int*)d_in[4];
  float* out = (float*)d_out;

  char* ws = (char*)d_ws;
  size_t off = 0;
  auto alloc = [&](size_t bytes) -> void* {
    void* p = ws + off;
    off += (bytes + 255) & ~(size_t)255;
    return p;
  };
  int* meta = (int*)alloc(64);
  int* poscount = (int*)alloc(512);
  unsigned short* Abf = (unsigned short*)alloc((size_t)B_ROWS * C_DIM * 2);
  float* scores = (float*)alloc((size_t)B_ROWS * K_QUEUE * 4);
  float* neg_sorted = (float*)alloc((size_t)B_ROWS * K_QUEUE * 4);
  int* bucket_off = (int*)alloc((size_t)B_ROWS * (NB + 1) * 4);
  float* pos_buf = (float*)alloc((size_t)B_ROWS * POS_CAP * 4);
  if (off > ws_size) return;  // fail loudly via validation rather than corrupt memory

  k_setup<<<1, 256, 0, stream>>>(label_q, label_queue, top_k, meta, poscount);
  k_cvtA<<<(B_ROWS * C_DIM + 255) / 256, 256, 0, stream>>>(liner_q, Abf);
  k_gemm<<<K_QUEUE / 64, 256, 0, stream>>>(Abf, feature_queue, scores);
  k_rowsort<<<B_ROWS, RS_THREADS, 0, stream>>>(scores, label_q, label_queue, neg_sorted,
                                               bucket_off, pos_buf);
  k_bsort<<<dim3(NB / BS_BUCKETS, B_ROWS), 256, 0, stream>>>(neg_sorted, bucket_off);
  k_psort<<<B_ROWS, 256, 0, stream>>>(pos_buf, poscount);
  k_assemble<<<dim3((K_QUEUE + ASM_COLS) / ASM_COLS, B_ROWS * 26), 256, 0, stream>>>(
      neg_sorted, pos_buf, meta, out);
}

// Round 2
// 1654.463 us; speedup vs baseline: 1.6300x; 1.2508x over previous
//
#include <hip/hip_runtime.h>
#include <stdint.h>

#define K_QUEUE 65536
#define B_ROWS 128
#define C_DIM 768
#define NB 8192          // value buckets per row for negative sort
#define POS_CAP 4096     // max positives per row we handle (actual ~1024)
#define RS_THREADS 512

static constexpr float INV_T = 1.0f / 0.3f;

typedef short s8v __attribute__((ext_vector_type(8)));
typedef float f4v __attribute__((ext_vector_type(4)));

__device__ __forceinline__ unsigned short f2bf(float f) {
  unsigned u = __builtin_bit_cast(unsigned, f);
  unsigned r = (u + 0x7FFFu + ((u >> 16) & 1u)) >> 16;  // round-to-nearest-even
  return (unsigned short)r;
}

// monotonic float->uint (ascending) and inverse
__device__ __forceinline__ unsigned ford(float f) {
  unsigned u = __builtin_bit_cast(unsigned, f);
  return (u & 0x80000000u) ? ~u : (u | 0x80000000u);
}
__device__ __forceinline__ float ford_inv(unsigned u) {
  unsigned v = (u & 0x80000000u) ? (u & 0x7FFFFFFFu) : ~u;
  return __builtin_bit_cast(float, v);
}

// ---------------- setup: label histogram -> pos_min/neg_min/reps ----------------
__global__ void k_setup(const int* __restrict__ label_q,
                        const int* __restrict__ label_queue,
                        const int* __restrict__ top_k_p,
                        int* __restrict__ meta, int* __restrict__ poscount) {
  __shared__ int hist[64];
  __shared__ int s_min, s_max;
  int t = threadIdx.x;
  if (t < 64) hist[t] = 0;
  if (t == 0) { s_min = 1 << 30; s_max = 0; }
  __syncthreads();
  for (int i = t; i < K_QUEUE; i += 256) atomicAdd(&hist[label_queue[i] & 63], 1);
  __syncthreads();
  if (t < B_ROWS) {
    int pc = hist[label_q[t] & 63];
    poscount[t] = pc;
    atomicMin(&s_min, pc);
    atomicMax(&s_max, pc);
  }
  __syncthreads();
  if (t == 0) {
    int pos_min = s_min;
    int neg_min = K_QUEUE - s_max;
    int tk = top_k_p[0];
    int reps = ((pos_min < tk) ? pos_min : tk) + 1;
    meta[0] = pos_min; meta[1] = neg_min; meta[2] = reps;
  }
}

// ---------------- convert liner_q fp32 -> bf16 ----------------
__global__ void k_cvtA(const float* __restrict__ A, unsigned short* __restrict__ Abf) {
  int i = blockIdx.x * blockDim.x + threadIdx.x;
  if (i < B_ROWS * C_DIM) Abf[i] = f2bf(A[i]);
}

// ---------------- GEMM: scores[128][65536] = A(128x768) * Bq(65536x768)^T ----------------
// block tile: M=128 (all rows) x N=64, 4 waves, each wave owns a 16-wide n-slice.
// mfma_f32_16x16x32_bf16: A frag A[m=lane&15][k=(lane>>4)*8+j]; B frag B[k][n=lane&15];
// D: col=lane&15, row=(lane>>4)*4+reg  (HW-verified mappings per guide m89/m91).
#define BK 32
#define LDA 48  // padded LDS row stride (elems); keeps 16B alignment, breaks pow2 conflicts
__global__ __launch_bounds__(256) void k_gemm(const unsigned short* __restrict__ Abf,
                                              const float* __restrict__ Bq,
                                              float* __restrict__ scores) {
  __shared__ unsigned short As[128 * LDA];
  __shared__ unsigned short Bs[64 * LDA];
  int t = threadIdx.x;
  int wave = t >> 6, lane = t & 63;
  int q = lane >> 4, lr = lane & 15;
  int n0 = blockIdx.x * 64;

  f4v acc[8];
#pragma unroll
  for (int i = 0; i < 8; i++) acc[i] = (f4v){0.f, 0.f, 0.f, 0.f};

  for (int k0 = 0; k0 < C_DIM; k0 += BK) {
    // stage A: 128x32 bf16 (512 chunks of 8 elems = 16B)
#pragma unroll
    for (int c = t; c < 512; c += 256) {
      int m = c >> 2, ko = (c & 3) * 8;
      s8v v = *(const s8v*)(Abf + (size_t)m * C_DIM + k0 + ko);
      *(s8v*)(As + m * LDA + ko) = v;
    }
    // stage B: 64x32, fp32 -> bf16 (512 chunks of 4 floats)
#pragma unroll
    for (int c = t; c < 512; c += 256) {
      int n = c >> 3, ko = (c & 7) * 4;
      float4 v = *(const float4*)(Bq + (size_t)(n0 + n) * C_DIM + k0 + ko);
      unsigned lo = (unsigned)f2bf(v.x) | ((unsigned)f2bf(v.y) << 16);
      unsigned hi = (unsigned)f2bf(v.z) | ((unsigned)f2bf(v.w) << 16);
      *(uint2*)(Bs + n * LDA + ko) = make_uint2(lo, hi);
    }
    __syncthreads();
    s8v bfrag = *(const s8v*)(Bs + (wave * 16 + lr) * LDA + q * 8);
#pragma unroll
    for (int mt = 0; mt < 8; mt++) {
      s8v afrag = *(const s8v*)(As + (mt * 16 + lr) * LDA + q * 8);
      acc[mt] = __builtin_amdgcn_mfma_f32_16x16x32_bf16(afrag, bfrag, acc[mt], 0, 0, 0);
    }
    __syncthreads();
  }
  int n = n0 + wave * 16 + lr;
#pragma unroll
  for (int mt = 0; mt < 8; mt++)
#pragma unroll
    for (int r = 0; r < 4; r++) {
      int m = mt * 16 + q * 4 + r;
      scores[(size_t)m * K_QUEUE + n] = acc[mt][r];
    }
}

// ---------------- per-row: compact positives, bucket-sort negatives ----------------
__global__ __launch_bounds__(RS_THREADS) void k_rowsort(
    const float* __restrict__ scores, const int* __restrict__ label_q,
    const int* __restrict__ label_queue, float* __restrict__ neg_sorted,
    int* __restrict__ bucket_off, float* __restrict__ pos_buf,
    unsigned* __restrict__ row_mm) {
  __shared__ unsigned hist[NB];
  __shared__ unsigned tsum[RS_THREADS];
  __shared__ unsigned s_minu, s_maxu;
  __shared__ int s_pcnt;

  int b = blockIdx.x, t = threadIdx.x;
  const float* row = scores + (size_t)b * K_QUEUE;
  int myl = label_q[b];

  if (t == 0) { s_minu = 0xFFFFFFFFu; s_maxu = 0u; s_pcnt = 0; }
  for (int i = t; i < NB; i += RS_THREADS) hist[i] = 0u;
  __syncthreads();

  // pass 0: neg min/max + compact positives (order arbitrary; sorted later)
  unsigned lmin = 0xFFFFFFFFu, lmax = 0u;
  for (int i = t * 4; i < K_QUEUE; i += RS_THREADS * 4) {
    float4 v4 = *(const float4*)(row + i);
    int4 l4 = *(const int4*)(label_queue + i);
    float vv[4] = {v4.x, v4.y, v4.z, v4.w};
    int ll[4] = {l4.x, l4.y, l4.z, l4.w};
#pragma unroll
    for (int j = 0; j < 4; j++) {
      if (ll[j] == myl) {
        int p = atomicAdd(&s_pcnt, 1);
        if (p < POS_CAP) pos_buf[(size_t)b * POS_CAP + p] = vv[j];
      } else {
        unsigned u = ford(vv[j]);
        lmin = min(lmin, u);
        lmax = max(lmax, u);
      }
    }
  }
  atomicMin(&s_minu, lmin);
  atomicMax(&s_maxu, lmax);
  __syncthreads();
  float minv = ford_inv(s_minu), maxv = ford_inv(s_maxu);
  float scale = (float)(NB - 1) / fmaxf(maxv - minv, 1e-30f);
  if (t == 0) { row_mm[b * 2] = s_minu; row_mm[b * 2 + 1] = s_maxu; }

  // pass 1: bucket histogram over negatives (descending buckets)
  for (int i = t * 4; i < K_QUEUE; i += RS_THREADS * 4) {
    float4 v4 = *(const float4*)(row + i);
    int4 l4 = *(const int4*)(label_queue + i);
    float vv[4] = {v4.x, v4.y, v4.z, v4.w};
    int ll[4] = {l4.x, l4.y, l4.z, l4.w};
#pragma unroll
    for (int j = 0; j < 4; j++) {
      if (ll[j] != myl) {
        int bk = (int)((maxv - vv[j]) * scale);
        bk = min(max(bk, 0), NB - 1);
        atomicAdd(&hist[bk], 1u);
      }
    }
  }
  __syncthreads();

  // pass 2: exclusive scan of 8192 bins (16 bins/thread + block scan)
  unsigned local[16];
  unsigned sum = 0;
#pragma unroll
  for (int j = 0; j < 16; j++) { local[j] = hist[t * 16 + j]; sum += local[j]; }
  tsum[t] = sum;
  __syncthreads();
  for (int off = 1; off < RS_THREADS; off <<= 1) {
    unsigned v = (t >= off) ? tsum[t - off] : 0u;
    __syncthreads();
    tsum[t] += v;
    __syncthreads();
  }
  unsigned run = tsum[t] - sum;
  int* boff = bucket_off + (size_t)b * (NB + 1);
#pragma unroll
  for (int j = 0; j < 16; j++) {
    unsigned c = local[j];
    hist[t * 16 + j] = run;       // scatter cursor
    boff[t * 16 + j] = (int)run;  // persisted for per-bucket sort
    run += c;
  }
  if (t == RS_THREADS - 1) boff[NB] = (int)run;  // = negcount
  __syncthreads();

  // pass 3: scatter negatives into bucket slots
  for (int i = t * 4; i < K_QUEUE; i += RS_THREADS * 4) {
    float4 v4 = *(const float4*)(row + i);
    int4 l4 = *(const int4*)(label_queue + i);
    float vv[4] = {v4.x, v4.y, v4.z, v4.w};
    int ll[4] = {l4.x, l4.y, l4.z, l4.w};
#pragma unroll
    for (int j = 0; j < 4; j++) {
      if (ll[j] != myl) {
        int bk = (int)((maxv - vv[j]) * scale);
        bk = min(max(bk, 0), NB - 1);
        unsigned p = atomicAdd(&hist[bk], 1u);
        neg_sorted[(size_t)b * K_QUEUE + p] = vv[j];
      }
    }
  }
}

// ---------------- per-bucket rank-scatter sort (descending) in LDS ----------------
// One block handles a contiguous chunk of BS_BUCKETS buckets (contiguous elements
// in neg_sorted). Chunk is loaded coalesced into LDS; each element then computes
// its final rank within its bucket by a short scan of INDEPENDENT LDS reads
// (no loop-carried dependence -> pipelined at LDS throughput, not the ~120cy
// dependent-chain latency that throttled the insertion-sort variant), and is
// scattered directly to global. Bucket id is recomputed bit-identically from the
// persisted row min/max. Overflow (never expected) falls back to global insertion.
#define BS_BUCKETS 256
#define BS_CAP 12288  // floats -> 48 KB LDS, 3 blocks/CU
__global__ __launch_bounds__(256) void k_bsort(float* __restrict__ neg_sorted,
                                               const int* __restrict__ bucket_off,
                                               const unsigned* __restrict__ row_mm) {
  __shared__ float sv[BS_CAP];
  __shared__ int sb[BS_BUCKETS + 1];
  int b = blockIdx.y;
  int bin0 = blockIdx.x * BS_BUCKETS;
  const int* boff = bucket_off + (size_t)b * (NB + 1);
  int t = threadIdx.x;
  // stage bucket offsets for this chunk
  sb[t] = boff[bin0 + t];
  if (t == 0) sb[BS_BUCKETS] = boff[bin0 + BS_BUCKETS];
  __syncthreads();
  int s = sb[0], e = sb[BS_BUCKETS];
  int n = e - s;
  float* a = neg_sorted + (size_t)b * K_QUEUE;
  float minv = ford_inv(row_mm[b * 2]);
  float maxv = ford_inv(row_mm[b * 2 + 1]);
  float scale = (float)(NB - 1) / fmaxf(maxv - minv, 1e-30f);

  if (n <= BS_CAP) {
    // coalesced load chunk into LDS
    for (int i = t; i < n; i += 256) sv[i] = a[s + i];
    __syncthreads();
    // per-element rank within its bucket, scatter to global
    for (int i = t; i < n; i += 256) {
      float v = sv[i];
      int bk = (int)((maxv - v) * scale);       // identical arithmetic to k_rowsort
      bk = min(max(bk, 0), NB - 1);
      int lb = bk - bin0;
      int bs_ = sb[lb] - s, be_ = sb[lb + 1] - s;
      int rank = 0;
      for (int j = bs_; j < be_; j++) {
        float w = sv[j];
        rank += (int)((w > v) || (w == v && j < i));
      }
      a[sb[lb] + rank] = v;
    }
  } else {
    // fallback: insertion sort in global memory (original path)
    int bs = sb[t], be = sb[t + 1];
    for (int i = bs + 1; i < be; i++) {
      float v = a[i];
      int j = i - 1;
      while (j >= bs && a[j] < v) { a[j + 1] = a[j]; j--; }
      a[j + 1] = v;
    }
  }
}

// ---------------- positives: bitonic sort (descending) per row in LDS ----------------
__global__ __launch_bounds__(256) void k_psort(float* __restrict__ pos_buf,
                                               const int* __restrict__ poscount) {
  __shared__ float sv[POS_CAP];
  int b = blockIdx.x, t = threadIdx.x;
  int pc = min(poscount[b], POS_CAP);
  // sort only the next power-of-two >= pc (actual pc ~1024, not POS_CAP)
  int M = 64;
  while (M < pc) M <<= 1;
  float* pb = pos_buf + (size_t)b * POS_CAP;
  for (int i = t; i < M; i += 256) sv[i] = (i < pc) ? pb[i] : -__builtin_inff();
  __syncthreads();
  for (int ksz = 2; ksz <= M; ksz <<= 1) {
    for (int j = ksz >> 1; j > 0; j >>= 1) {
      for (int e = t; e < M; e += 256) {
        int p = e ^ j;
        if (p > e) {
          bool up = (e & ksz) != 0;  // ascending region; final pass: descending
          float a0 = sv[e], a1 = sv[p];
          bool sw = up ? (a0 > a1) : (a0 < a1);
          if (sw) { sv[e] = a1; sv[p] = a0; }
        }
      }
      __syncthreads();
    }
  }
  for (int i = t; i < M; i += 256) pb[i] = sv[i];
}

// ---------------- assemble output: out[b*reps+r] = [pos_cat, neg_sorted[b][0:neg_min]] / T --
// float4 stores aligned on the OUTPUT (the HBM-bound side); ns reads hit L2 (each
// row's 258 KB is reused 26x).
#define ASM_COLS 4096
__global__ __launch_bounds__(256) void k_assemble(const float* __restrict__ neg_sorted,
                                                  const float* __restrict__ pos_buf,
                                                  const int* __restrict__ meta,
                                                  float* __restrict__ out) {
  int pos_min = meta[0], neg_min = meta[1], reps = meta[2];
  int row = blockIdx.y;
  if (row >= B_ROWS * reps) return;
  int L = 1 + neg_min;
  int c0 = blockIdx.x * ASM_COLS;
  if (c0 >= L) return;
  int b = row / reps;
  int r = row - b * reps;
  size_t obase = (size_t)row * (size_t)L;
  const float* ns = neg_sorted + (size_t)b * K_QUEUE;
  float* orow = out + obase;
  int t = threadIdx.x;
  if (c0 == 0 && t == 0) {
    const float* pb = pos_buf + (size_t)b * POS_CAP;
    float pv = (r < reps - 1) ? pb[r] : pb[pos_min - 1];
    orow[0] = pv * INV_T;
  }
  int cstart = (c0 < 1) ? 1 : c0;
  int cend = min(c0 + ASM_COLS, L);
  if (cstart >= cend) return;
  int ca = (int)((4 - (obase & 3)) & 3);  // residue mod 4 making out addr 16B-aligned
  int calign = cstart + (int)(((unsigned)(ca - cstart)) & 3u);
  if (calign > cend) calign = cend;
  int nvec = (cend - calign) >> 2;
  int tail0 = calign + (nvec << 2);
  // head (<=3 scalars)
  for (int c = cstart + t; c < calign; c += 256) orow[c] = ns[c - 1] * INV_T;
  // aligned float4 body
  for (int k = t; k < nvec; k += 256) {
    int c = calign + (k << 2);
    float4 w;
    w.x = ns[c - 1] * INV_T;
    w.y = ns[c] * INV_T;
    w.z = ns[c + 1] * INV_T;
    w.w = ns[c + 2] * INV_T;
    *(float4*)(orow + c) = w;
  }
  // tail (<=3 scalars)
  for (int c = tail0 + t; c < cend; c += 256) orow[c] = ns[c - 1] * INV_T;
}

// ---------------- launch ----------------
extern "C" void kernel_launch(void* const* d_in, const int* in_sizes, int n_in,
                              void* d_out, int out_size, void* d_ws, size_t ws_size,
                              hipStream_t stream) {
  const float* liner_q = (const float*)d_in[0];
  const float* feature_queue = (const float*)d_in[1];
  const int* label_q = (const int*)d_in[2];
  const int* label_queue = (const int*)d_in[3];
  const int* top_k = (const int*)d_in[4];
  float* out = (float*)d_out;

  char* ws = (char*)d_ws;
  size_t off = 0;
  auto alloc = [&](size_t bytes) -> void* {
    void* p = ws + off;
    off += (bytes + 255) & ~(size_t)255;
    return p;
  };
  int* meta = (int*)alloc(64);
  int* poscount = (int*)alloc(512);
  unsigned* row_mm = (unsigned*)alloc((size_t)B_ROWS * 2 * 4);
  unsigned short* Abf = (unsigned short*)alloc((size_t)B_ROWS * C_DIM * 2);
  float* scores = (float*)alloc((size_t)B_ROWS * K_QUEUE * 4);
  float* neg_sorted = (float*)alloc((size_t)B_ROWS * K_QUEUE * 4);
  int* bucket_off = (int*)alloc((size_t)B_ROWS * (NB + 1) * 4);
  float* pos_buf = (float*)alloc((size_t)B_ROWS * POS_CAP * 4);
  if (off > ws_size) return;  // fail loudly via validation rather than corrupt memory

  k_setup<<<1, 256, 0, stream>>>(label_q, label_queue, top_k, meta, poscount);
  k_cvtA<<<(B_ROWS * C_DIM + 255) / 256, 256, 0, stream>>>(liner_q, Abf);
  k_gemm<<<K_QUEUE / 64, 256, 0, stream>>>(Abf, feature_queue, scores);
  k_rowsort<<<B_ROWS, RS_THREADS, 0, stream>>>(scores, label_q, label_queue, neg_sorted,
                                               bucket_off, pos_buf, row_mm);
  k_bsort<<<dim3(NB / BS_BUCKETS, B_ROWS), 256, 0, stream>>>(neg_sorted, bucket_off, row_mm);
  k_psort<<<B_ROWS, 256, 0, stream>>>(pos_buf, poscount);
  k_assemble<<<dim3((K_QUEUE + ASM_COLS) / ASM_COLS, B_ROWS * 26), 256, 0, stream>>>(
      neg_sorted, pos_buf, meta, out);
}